// Round 2
// baseline (461.258 us; speedup 1.0000x reference)
//
#include <hip/hip_runtime.h>
#include <hip/hip_bf16.h>

// Problem constants (fixed by setup_inputs): B=8, T=2048, D=1024, positions in [0,64).
#define NB 8
#define NT 2048
#define ND 1024
#define CAP 2048       // max tokens per bucket (worst case all T in one bucket)

// ---------------------------------------------------------------------------
// Workspace layout (byte offsets, all 512-aligned):
//   G2f    : 128 floats  g2[k] = exp(-(k-63)^2/512), valid k in [0,126]   @ 0
//   cntv   : NB*64 int                                                    @ 512
//   cnth   : NB*64 int                                                    @ 2560
//   cntB1T : NB*64*64 float  [b][ph][pv] count-conv (transposed)          @ 4608
//   invden : NB*NT float     per-token 1/denominator                      @ 135680
//   tokv   : NB*64*CAP int   (token ids bucketed by posv)                 @ 201216
//   tokh   : NB*64*CAP int   (token ids bucketed by posh)                 @ 4395520
//   B1     : (NB or 1)*64*64*1024 float                                   @ 8589824
// ---------------------------------------------------------------------------
#define OFF_G2     0
#define OFF_CNTV   512
#define OFF_CNTH   2560
#define OFF_CNTB1T 4608
#define OFF_INVDEN 135680
#define OFF_TOKV   201216
#define OFF_TOKH   4395520
#define OFF_B1     8589824
#define B1_SLAB    ((size_t)64 * 64 * 1024 * 4)   // bytes per batch slab (16 MB)

// K1: deterministic CSR bucket lists (by posv and by posh) via wave ballot
// compaction (no atomics -> bitwise deterministic). Block 0 fills the g table.
// One task (bucket,axis) per wave; 32 pos values preloaded into registers.
__global__ __launch_bounds__(256) void k1_bucket(
    const int* __restrict__ posv, const int* __restrict__ posh,
    int* __restrict__ tokv, int* __restrict__ tokh,
    int* __restrict__ cntv, int* __restrict__ cnth,
    float* __restrict__ G2f)
{
    int b    = blockIdx.x >> 5;      // NB*32 blocks
    int blk  = blockIdx.x & 31;
    int wave = threadIdx.x >> 6;
    int lane = threadIdx.x & 63;

    if (blockIdx.x == 0 && threadIdx.x < 128) {
        int k = (int)threadIdx.x;
        if (k < 127) {
            int r = k - 63;
            G2f[k] = expf(-(float)(r * r) * (1.0f / 512.0f));
        } else {
            G2f[k] = 0.0f;
        }
    }

    int task   = blk * 4 + wave;                // 0..127
    int bucket = task & 63;
    int use_ph = task >> 6;
    const int* pos = use_ph ? posh : posv;
    int* tok = (use_ph ? tokh : tokv) + ((size_t)(b * 64 + bucket)) * CAP;
    int* cnt = use_ph ? cnth : cntv;

    int vals[32];
#pragma unroll
    for (int k = 0; k < 32; k++) vals[k] = pos[b * NT + k * 64 + lane];

    unsigned long long lmask = (1ull << lane) - 1ull;
    int cursor = 0;
#pragma unroll 4
    for (int k = 0; k < 32; k++) {
        bool hit = (vals[k] == bucket);
        unsigned long long m = __ballot(hit);
        if (hit) tok[cursor + __popcll(m & lmask)] = k * 64 + lane;
        cursor += (int)__popcll(m);
    }
    if (lane == 0) cnt[b * 64 + bucket] = cursor;
}

// K2: h-direction conv from token lists:
//   B1[b][pv][ph][d] = sum_{t: posv_t==pv} g(ph - posh_t) * x[b][t][d]
// Thread owns one d, register-accumulates all 64 ph. Tokens processed in
// chunks of 8: loads issued together (ILP), then 512 FMAs. g-window reads
// are wave-uniform (readfirstlane'd ph -> s_loads). launch_bounds(,4) caps
// VGPR at 128 so acc[64] stays in registers (round-1 strip-mine fix).
// Also emits cntB1T[b][ph][pv] = sum_t g(ph - posh_t), wave-parallel.
__global__ __launch_bounds__(256, 4) void k2_convh(
    const float* __restrict__ x, const int* __restrict__ posh,
    const int* __restrict__ tokv, const int* __restrict__ cntv,
    const float* __restrict__ G2f, float* __restrict__ B1,
    float* __restrict__ cntB1T, int b0)
{
    int p    = blockIdx.x & 63;
    int b    = b0 + (blockIdx.x >> 6);
    int tid  = threadIdx.x;
    int d    = (blockIdx.y << 8) + tid;
    int lane = tid & 63;
    int wav  = tid >> 6;

    int n = cntv[b * 64 + p];
    const int* toks = tokv + ((size_t)(b * 64 + p)) * CAP;
    const float* xb = x + (((size_t)b * NT) << 10) + d;

    __shared__ int   s_t[256];
    __shared__ int   s_ph[256];
    __shared__ float s_g2[128];
    __shared__ float s_cpart[4][64];

    if (blockIdx.y == 0 && tid < 128) s_g2[tid] = G2f[tid];
    float cpart = 0.0f;

    float acc[64];
#pragma unroll
    for (int q = 0; q < 64; q++) acc[q] = 0.0f;

    for (int base = 0; base < n; base += 256) {
        int m = min(256, n - base);
        __syncthreads();
        if (tid < m) {
            int t = toks[base + tid];
            s_t[tid]  = t;
            s_ph[tid] = posh[b * NT + t];
        }
        __syncthreads();
        int i = 0;
        for (; i + 8 <= m; i += 8) {
            float xv[8]; int phx[8];
#pragma unroll
            for (int j = 0; j < 8; j++) {
                int t  = __builtin_amdgcn_readfirstlane(s_t[i + j]);
                phx[j] = __builtin_amdgcn_readfirstlane(s_ph[i + j]);
                xv[j]  = xb[(size_t)t << 10];
            }
#pragma unroll
            for (int q = 0; q < 64; q++) {
                float a = acc[q];
#pragma unroll
                for (int j = 0; j < 8; j++)
                    a = fmaf(G2f[63 - phx[j] + q], xv[j], a);
                acc[q] = a;
            }
        }
        for (; i < m; i++) {
            int t  = __builtin_amdgcn_readfirstlane(s_t[i]);
            int ph = __builtin_amdgcn_readfirstlane(s_ph[i]);
            float xvs = xb[(size_t)t << 10];
#pragma unroll
            for (int q = 0; q < 64; q++)
                acc[q] = fmaf(G2f[63 - ph + q], xvs, acc[q]);
        }
        if (blockIdx.y == 0) {
            // count-conv, wave-parallel: wave `wav` takes tokens i2 = wav, wav+4, ...
            for (int i2 = wav; i2 < m; i2 += 4)
                cpart += s_g2[63 + lane - s_ph[i2]];   // s_ph read is broadcast
        }
    }

    float* B1b = B1 + (((size_t)(b - b0)) << 22) + d;
#pragma unroll
    for (int q = 0; q < 64; q++)
        B1b[(size_t)(p * 64 + q) << 10] = acc[q];

    if (blockIdx.y == 0) {
        s_cpart[wav][lane] = cpart;
        __syncthreads();
        if (tid < 64)
            cntB1T[(b * 64 + tid) * 64 + p] =
                s_cpart[0][tid] + s_cpart[1][tid] + s_cpart[2][tid] + s_cpart[3][tid];
    }
}

// K2b: per-token inverse denominator:
//   invden[b][t] = 1 / sum_j g(j - posv_t) * cntB1T[b][posh_t][j]
__global__ __launch_bounds__(256) void k2b_denom(
    const int* __restrict__ posv, const int* __restrict__ posh,
    const float* __restrict__ G2f, const float* __restrict__ cntB1T,
    float* __restrict__ invden, int b0)
{
    int idx = b0 * NT + blockIdx.x * 256 + threadIdx.x;   // b*NT + t
    int b   = idx >> 11;
    int pv  = posv[idx];
    int ph  = posh[idx];
    const float* crow = cntB1T + (b * 64 + ph) * 64;
    const float* gw   = G2f + (63 - pv);
    float a0 = 0.f, a1 = 0.f, a2 = 0.f, a3 = 0.f;
#pragma unroll
    for (int j = 0; j < 64; j += 4) {
        a0 = fmaf(gw[j + 0], crow[j + 0], a0);
        a1 = fmaf(gw[j + 1], crow[j + 1], a1);
        a2 = fmaf(gw[j + 2], crow[j + 2], a2);
        a3 = fmaf(gw[j + 3], crow[j + 3], a3);
    }
    invden[idx] = 1.0f / ((a0 + a1) + (a2 + a3));
}

// K3: v-direction conv fused with per-token gather + normalization:
//   out[b][t][d] = invden[t] * sum_j g(j - posv_t) * B1[b][j][posh_t][d]
// B1 column register-resident (64 regs/thread); tokens in chunks of 4 with
// 2 FMA chains each (8 independent chains). launch_bounds(,4) as in k2.
__global__ __launch_bounds__(256, 4) void k3_convv(
    const int* __restrict__ posv,
    const int* __restrict__ tokh, const int* __restrict__ cnth,
    const float* __restrict__ G2f, const float* __restrict__ B1,
    const float* __restrict__ invden, float* __restrict__ out, int b0)
{
    int p   = blockIdx.x & 63;          // ph bucket
    int b   = b0 + (blockIdx.x >> 6);
    int tid = threadIdx.x;
    int d   = (blockIdx.y << 8) + tid;

    int n = cnth[b * 64 + p];
    if (n == 0) return;                 // uniform across block: safe

    const int* toks = tokh + ((size_t)(b * 64 + p)) * CAP;
    const float* B1b = B1 + (((size_t)(b - b0)) << 22) + d;
    float* outb = out + (((size_t)b * NT) << 10) + d;

    float col[64];
#pragma unroll
    for (int j = 0; j < 64; j++)
        col[j] = B1b[(size_t)(j * 64 + p) << 10];

    __shared__ int   s_t[256];
    __shared__ int   s_pv[256];
    __shared__ float s_inv[256];

    for (int base = 0; base < n; base += 256) {
        int m = min(256, n - base);
        __syncthreads();
        if (tid < m) {
            int t = toks[base + tid];
            s_t[tid]   = t;
            s_pv[tid]  = posv[b * NT + t];
            s_inv[tid] = invden[b * NT + t];
        }
        __syncthreads();
        int i = 0;
        for (; i + 4 <= m; i += 4) {
            int t4[4], pv4[4]; float iv4[4];
#pragma unroll
            for (int j = 0; j < 4; j++) {
                t4[j]  = __builtin_amdgcn_readfirstlane(s_t[i + j]);
                pv4[j] = __builtin_amdgcn_readfirstlane(s_pv[i + j]);
                iv4[j] = s_inv[i + j];
            }
            float a[4][2];
#pragma unroll
            for (int j = 0; j < 4; j++) { a[j][0] = 0.f; a[j][1] = 0.f; }
#pragma unroll
            for (int q = 0; q < 64; q += 2) {
#pragma unroll
                for (int j = 0; j < 4; j++) {
                    a[j][0] = fmaf(G2f[63 - pv4[j] + q],     col[q],     a[j][0]);
                    a[j][1] = fmaf(G2f[63 - pv4[j] + q + 1], col[q + 1], a[j][1]);
                }
            }
#pragma unroll
            for (int j = 0; j < 4; j++)
                outb[(size_t)t4[j] << 10] = (a[j][0] + a[j][1]) * iv4[j];
        }
        for (; i < m; i++) {
            int t  = __builtin_amdgcn_readfirstlane(s_t[i]);
            int pv = __builtin_amdgcn_readfirstlane(s_pv[i]);
            float iv = s_inv[i];
            float a0 = 0.f, a1 = 0.f;
#pragma unroll
            for (int q = 0; q < 64; q += 2) {
                a0 = fmaf(G2f[63 - pv + q],     col[q],     a0);
                a1 = fmaf(G2f[63 - pv + q + 1], col[q + 1], a1);
            }
            outb[(size_t)t << 10] = (a0 + a1) * iv;
        }
    }
}

// Safety-net fallback (no workspace needed): direct O(T^2 * D) attention.
__global__ __launch_bounds__(256) void k_naive(
    const float* __restrict__ x, const int* __restrict__ posv,
    const int* __restrict__ posh, float* __restrict__ out)
{
    int t   = blockIdx.x & (NT - 1);
    int b   = blockIdx.x >> 11;
    int tid = threadIdx.x;

    __shared__ float s_w[NT];
    __shared__ float s_red[256];

    int pvt = posv[b * NT + t];
    int pht = posh[b * NT + t];

    float dsum = 0.0f;
    for (int s = tid; s < NT; s += 256) {
        int dv = pvt - posv[b * NT + s];
        int dh = pht - posh[b * NT + s];
        float w = expf(-(float)(dv * dv + dh * dh) * (1.0f / 512.0f));
        s_w[s] = w;
        dsum += w;
    }
    s_red[tid] = dsum;
    __syncthreads();
    for (int off = 128; off > 0; off >>= 1) {
        if (tid < off) s_red[tid] += s_red[tid + off];
        __syncthreads();
    }
    float inv = 1.0f / s_red[0];

    float a0 = 0.f, a1 = 0.f, a2 = 0.f, a3 = 0.f;
    for (int s = 0; s < NT; s++) {
        float w = s_w[s];
        const float* xr = x + (((size_t)(b * NT + s)) << 10);
        a0 = fmaf(w, xr[tid + 0],   a0);
        a1 = fmaf(w, xr[tid + 256], a1);
        a2 = fmaf(w, xr[tid + 512], a2);
        a3 = fmaf(w, xr[tid + 768], a3);
    }
    size_t ob = (((size_t)(b * NT + t)) << 10) + tid;
    out[ob + 0]   = a0 * inv;
    out[ob + 256] = a1 * inv;
    out[ob + 512] = a2 * inv;
    out[ob + 768] = a3 * inv;
}

extern "C" void kernel_launch(void* const* d_in, const int* in_sizes, int n_in,
                              void* d_out, int out_size, void* d_ws, size_t ws_size,
                              hipStream_t stream) {
    const float* x    = (const float*)d_in[0];
    const int*   posv = (const int*)d_in[1];
    const int*   posh = (const int*)d_in[2];
    float*       out  = (float*)d_out;

    char* ws = (char*)d_ws;
    float* G2f    = (float*)(ws + OFF_G2);
    int*   cntv   = (int*)(ws + OFF_CNTV);
    int*   cnth   = (int*)(ws + OFF_CNTH);
    float* cntB1T = (float*)(ws + OFF_CNTB1T);
    float* invden = (float*)(ws + OFF_INVDEN);
    int*   tokv   = (int*)(ws + OFF_TOKV);
    int*   tokh   = (int*)(ws + OFF_TOKH);
    float* B1     = (float*)(ws + OFF_B1);

    const size_t needFull = (size_t)OFF_B1 + (size_t)NB * B1_SLAB;   // ~143 MB
    const size_t needLoop = (size_t)OFF_B1 + B1_SLAB;                // ~25 MB

    if (ws_size >= needFull) {
        k1_bucket<<<NB * 32, 256, 0, stream>>>(posv, posh, tokv, tokh, cntv, cnth, G2f);
        k2_convh<<<dim3(NB * 64, ND / 256), 256, 0, stream>>>(
            x, posh, tokv, cntv, G2f, B1, cntB1T, 0);
        k2b_denom<<<NB * NT / 256, 256, 0, stream>>>(posv, posh, G2f, cntB1T, invden, 0);
        k3_convv<<<dim3(NB * 64, ND / 256), 256, 0, stream>>>(
            posv, tokh, cnth, G2f, B1, invden, out, 0);
    } else if (ws_size >= needLoop) {
        k1_bucket<<<NB * 32, 256, 0, stream>>>(posv, posh, tokv, tokh, cntv, cnth, G2f);
        for (int b = 0; b < NB; b++) {
            k2_convh<<<dim3(64, ND / 256), 256, 0, stream>>>(
                x, posh, tokv, cntv, G2f, B1, cntB1T, b);
            k2b_denom<<<NT / 256, 256, 0, stream>>>(posv, posh, G2f, cntB1T, invden, b);
            k3_convv<<<dim3(64, ND / 256), 256, 0, stream>>>(
                posv, tokh, cnth, G2f, B1, invden, out, b);
        }
    } else {
        k_naive<<<NB * NT, 256, 0, stream>>>(x, posv, posh, out);
    }
}

// Round 3
// 215.818 us; speedup vs baseline: 2.1373x; 2.1373x over previous
//
#include <hip/hip_runtime.h>
#include <hip/hip_bf16.h>

// Problem constants (fixed by setup_inputs): B=8, T=2048, D=1024, positions in [0,64).
#define NB 8
#define NT 2048
#define ND 1024
#define CAP 2048       // max tokens per bucket (worst case all T in one bucket)

// ---------------------------------------------------------------------------
// Workspace layout (byte offsets):
//   G2f    : 128 floats  g2[k] = exp(-(k-63)^2/512), valid k in [0,126]   @ 0
//   cntv   : NB*64 int                                                    @ 512
//   cnth   : NB*64 int                                                    @ 2560
//   invden : NB*64*64 float  1/denominator for a token at (pv,ph)         @ 4608
//   tokv   : NB*64*CAP int   (token ids bucketed by posv)                 @ 135680
//   tokh   : NB*64*CAP int   (token ids bucketed by posh)                 @ 4329984
//   B1     : (NB or 1)*64*64*1024 float   [b][pv][q=ph'][d]              @ 8524288
// ---------------------------------------------------------------------------
#define OFF_G2     0
#define OFF_CNTV   512
#define OFF_CNTH   2560
#define OFF_INVDEN 4608
#define OFF_TOKV   135680
#define OFF_TOKH   4329984
#define OFF_B1     8524288
#define B1_SLAB    ((size_t)64 * 64 * 1024 * 4)   // bytes per batch slab (16 MB)

// K1: deterministic CSR bucket lists (by posv and by posh) via wave ballot
// compaction (no atomics in the compaction -> bitwise deterministic).
// Block 0 fills the g table. One (bucket,axis) task per wave.
__global__ __launch_bounds__(256) void k1_bucket(
    const int* __restrict__ posv, const int* __restrict__ posh,
    int* __restrict__ tokv, int* __restrict__ tokh,
    int* __restrict__ cntv, int* __restrict__ cnth,
    float* __restrict__ G2f)
{
    int b    = blockIdx.x >> 5;      // NB*32 blocks
    int blk  = blockIdx.x & 31;
    int wave = threadIdx.x >> 6;
    int lane = threadIdx.x & 63;

    if (blockIdx.x == 0 && threadIdx.x < 128) {
        int k = (int)threadIdx.x;
        if (k < 127) {
            int r = k - 63;
            G2f[k] = expf(-(float)(r * r) * (1.0f / 512.0f));
        } else {
            G2f[k] = 0.0f;
        }
    }

    int task   = blk * 4 + wave;                // 0..127
    int bucket = task & 63;
    int use_ph = task >> 6;
    const int* pos = use_ph ? posh : posv;
    int* tok = (use_ph ? tokh : tokv) + ((size_t)(b * 64 + bucket)) * CAP;
    int* cnt = use_ph ? cnth : cntv;

    int vals[32];
#pragma unroll
    for (int k = 0; k < 32; k++) vals[k] = pos[b * NT + k * 64 + lane];

    unsigned long long lmask = (1ull << lane) - 1ull;
    int cursor = 0;
#pragma unroll 4
    for (int k = 0; k < 32; k++) {
        bool hit = (vals[k] == bucket);
        unsigned long long m = __ballot(hit);
        if (hit) tok[cursor + __popcll(m & lmask)] = k * 64 + lane;
        cursor += (int)__popcll(m);
    }
    if (lane == 0) cnt[b * 64 + bucket] = cursor;
}

// KDEN: denominator table. den[pv][ph] = sum_{j,k} hist[j][k] g(pv-j) g(ph-k).
// Integer LDS-atomic histogram (deterministic), then two 64x64 mini-matmuls.
// Grid: NBat*8 blocks; block (b, ph-group of 8).
__global__ __launch_bounds__(256) void kden(
    const int* __restrict__ posv, const int* __restrict__ posh,
    const float* __restrict__ G2f, float* __restrict__ invden, int b0)
{
    int b   = b0 + (blockIdx.x >> 3);
    int phg = blockIdx.x & 7;
    int tid = threadIdx.x;

    __shared__ int   hist[64][64];
    __shared__ float g2s[128];
    __shared__ float tmp[64][8];

#pragma unroll
    for (int k = 0; k < 16; k++) ((int*)hist)[tid + (k << 8)] = 0;
    if (tid < 128) g2s[tid] = G2f[tid];
    __syncthreads();
#pragma unroll
    for (int k = 0; k < 8; k++) {
        int t = (k << 8) + tid;
        atomicAdd(&hist[posv[b * NT + t]][posh[b * NT + t]], 1);
    }
    __syncthreads();
    // phase 1: tmp[j][phl] = sum_k hist[j][k] * g(ph - k)
#pragma unroll
    for (int c = 0; c < 2; c++) {
        int cell = (c << 8) + tid;        // 512 cells: 64 j x 8 phl
        int j    = cell >> 3;
        int phl  = cell & 7;
        int ph   = (phg << 3) + phl;
        float s = 0.f;
        for (int k = 0; k < 64; k++)
            s += (float)hist[j][k] * g2s[63 + k - ph];
        tmp[j][phl] = s;
    }
    __syncthreads();
    // phase 2: den[pv][ph] = sum_j g(pv - j) * tmp[j][phl]
#pragma unroll
    for (int c = 0; c < 2; c++) {
        int cell = (c << 8) + tid;
        int pv   = cell >> 3;
        int phl  = cell & 7;
        int ph   = (phg << 3) + phl;
        float s = 0.f;
        for (int j = 0; j < 64; j++)
            s += g2s[63 + j - pv] * tmp[j][phl];
        invden[(b * 64 + pv) * 64 + ph] = 1.0f / s;
    }
}

// K2: h-conv from token lists.
//   B1[b][pv][q][d] = sum_{t: posv_t==pv} g(q - posh_t) * x[b][t][d]
// Wave w owns q-tile [16w,16w+16); lane owns d within a 64-wide d-chunk.
// Per-thread state: acc[16] (~40 VGPR) -> nothing for the compiler to
// strip-mine (the round-1/2 failure). g-window via readfirstlane'd ph
// -> uniform scalar loads. x loads 4x-redundant across waves (L1-absorbed).
// blockIdx.x = ((b-b0)<<10) | (dc<<6) | pv.
__global__ __launch_bounds__(256) void k2_convh(
    const float* __restrict__ x, const int* __restrict__ posh,
    const int* __restrict__ tokv, const int* __restrict__ cntv,
    const float* __restrict__ G2f, float* __restrict__ B1, int b0)
{
    int pv   = blockIdx.x & 63;
    int dc   = (blockIdx.x >> 6) & 15;
    int b    = b0 + (blockIdx.x >> 10);
    int tid  = threadIdx.x;
    int lane = tid & 63;
    int w    = tid >> 6;
    int d0   = dc << 6;

    int n = cntv[b * 64 + pv];
    const int* toks = tokv + ((size_t)(b * 64 + pv)) * CAP;
    const float* xb = x + (((size_t)b * NT) << 10) + d0 + lane;
    const float* gq = G2f + 63 + (w << 4);    // gq[q - ph] for q in tile

    float acc[16];
#pragma unroll
    for (int q = 0; q < 16; q++) acc[q] = 0.f;

    __shared__ int s_t[256];
    __shared__ int s_ph[256];

    for (int base = 0; base < n; base += 256) {
        int m = min(256, n - base);
        __syncthreads();
        if (tid < m) {
            int t = toks[base + tid];
            s_t[tid]  = t;
            s_ph[tid] = posh[b * NT + t];
        }
        __syncthreads();
        int i = 0;
        for (; i + 4 <= m; i += 4) {
            float xv[4]; const float* gp[4];
#pragma unroll
            for (int j = 0; j < 4; j++) {
                int t  = __builtin_amdgcn_readfirstlane(s_t[i + j]);
                int ph = __builtin_amdgcn_readfirstlane(s_ph[i + j]);
                xv[j] = xb[(size_t)t << 10];
                gp[j] = gq - ph;
            }
#pragma unroll
            for (int q = 0; q < 16; q++) {
                float a = acc[q];
#pragma unroll
                for (int j = 0; j < 4; j++)
                    a = fmaf(gp[j][q], xv[j], a);
                acc[q] = a;
            }
        }
        for (; i < m; i++) {
            int t  = __builtin_amdgcn_readfirstlane(s_t[i]);
            int ph = __builtin_amdgcn_readfirstlane(s_ph[i]);
            float xv = xb[(size_t)t << 10];
            const float* gp = gq - ph;
#pragma unroll
            for (int q = 0; q < 16; q++)
                acc[q] = fmaf(gp[q], xv, acc[q]);
        }
    }

    // B1 index = ((pv*64 + q)*1024 + d); q = 16w + i
    float* B1p = B1 + (((size_t)(b - b0)) << 22) + (((size_t)pv) << 16)
               + (((size_t)(w << 4)) << 10) + d0 + lane;
#pragma unroll
    for (int q = 0; q < 16; q++)
        B1p[(size_t)q << 10] = acc[q];
}

// K3: dense v-conv fused with token gather + normalization.
// Per (b, ph, dchunk) block: stage u[j][d] = B1[b][j][ph][d] into LDS,
// compute y[pv'][d] = sum_j g(pv'-j) u[j][d] (wave q-tiles, acc[16]),
// park y in LDS, then scatter: out[t][d] = y[pv_t][d] * invden[pv_t][ph].
__global__ __launch_bounds__(256) void k3_convv(
    const int* __restrict__ posv,
    const int* __restrict__ tokh, const int* __restrict__ cnth,
    const float* __restrict__ G2f, const float* __restrict__ B1,
    const float* __restrict__ invden, float* __restrict__ out, int b0)
{
    int ph   = blockIdx.x & 63;
    int dc   = (blockIdx.x >> 6) & 15;
    int b    = b0 + (blockIdx.x >> 10);
    int tid  = threadIdx.x;
    int lane = tid & 63;
    int w    = tid >> 6;
    int d0   = dc << 6;

    int n = cnth[b * 64 + ph];
    if (n == 0) return;               // uniform across block: safe

    __shared__ float u[64][64];
    __shared__ float y[64][64];
    __shared__ int   s_t[256];
    __shared__ int   s_pv[256];
    __shared__ float s_iv[256];

    // stage u: 16 independent 256B wave-loads per wave
    const float* B1p = B1 + (((size_t)(b - b0)) << 22) + (((size_t)ph) << 10)
                     + d0 + lane;
#pragma unroll
    for (int k = 0; k < 16; k++) {
        int j = (k << 2) + w;
        u[j][lane] = B1p[(size_t)j << 16];
    }
    __syncthreads();

    // dense 64-tap v-conv: wave w computes y[16w .. 16w+16)
    float acc[16];
#pragma unroll
    for (int q = 0; q < 16; q++) acc[q] = 0.f;
    const float* gq = G2f + 63 + (w << 4);
    for (int j = 0; j < 64; j += 4) {
        float uv[4];
#pragma unroll
        for (int jj = 0; jj < 4; jj++) uv[jj] = u[j + jj][lane];
#pragma unroll
        for (int q = 0; q < 16; q++) {
            float a = acc[q];
#pragma unroll
            for (int jj = 0; jj < 4; jj++)
                a = fmaf(gq[q - (j + jj)], uv[jj], a);
            acc[q] = a;
        }
    }
#pragma unroll
    for (int q = 0; q < 16; q++) y[(w << 4) + q][lane] = acc[q];
    // first __syncthreads in the scatter loop orders y-writes vs y-reads

    const int* toks = tokh + ((size_t)(b * 64 + ph)) * CAP;
    float* outb = out + (((size_t)b * NT) << 10) + d0 + lane;
    const float* ivb = invden + (b * 64) * 64 + ph;

    for (int base = 0; base < n; base += 256) {
        int m = min(256, n - base);
        __syncthreads();
        if (tid < m) {
            int t  = toks[base + tid];
            int pv = posv[b * NT + t];
            s_t[tid]  = t;
            s_pv[tid] = pv;
            s_iv[tid] = ivb[pv * 64];
        }
        __syncthreads();
        for (int i = w; i < m; i += 4) {
            int t  = __builtin_amdgcn_readfirstlane(s_t[i]);
            int pv = __builtin_amdgcn_readfirstlane(s_pv[i]);
            float iv = s_iv[i];
            outb[(size_t)t << 10] = y[pv][lane] * iv;
        }
    }
}

// Safety-net fallback (no workspace needed): direct O(T^2 * D) attention.
__global__ __launch_bounds__(256) void k_naive(
    const float* __restrict__ x, const int* __restrict__ posv,
    const int* __restrict__ posh, float* __restrict__ out)
{
    int t   = blockIdx.x & (NT - 1);
    int b   = blockIdx.x >> 11;
    int tid = threadIdx.x;

    __shared__ float s_w[NT];
    __shared__ float s_red[256];

    int pvt = posv[b * NT + t];
    int pht = posh[b * NT + t];

    float dsum = 0.0f;
    for (int s = tid; s < NT; s += 256) {
        int dv = pvt - posv[b * NT + s];
        int dh = pht - posh[b * NT + s];
        float w = expf(-(float)(dv * dv + dh * dh) * (1.0f / 512.0f));
        s_w[s] = w;
        dsum += w;
    }
    s_red[tid] = dsum;
    __syncthreads();
    for (int off = 128; off > 0; off >>= 1) {
        if (tid < off) s_red[tid] += s_red[tid + off];
        __syncthreads();
    }
    float inv = 1.0f / s_red[0];

    float a0 = 0.f, a1 = 0.f, a2 = 0.f, a3 = 0.f;
    for (int s = 0; s < NT; s++) {
        float w = s_w[s];
        const float* xr = x + (((size_t)(b * NT + s)) << 10);
        a0 = fmaf(w, xr[tid + 0],   a0);
        a1 = fmaf(w, xr[tid + 256], a1);
        a2 = fmaf(w, xr[tid + 512], a2);
        a3 = fmaf(w, xr[tid + 768], a3);
    }
    size_t ob = (((size_t)(b * NT + t)) << 10) + tid;
    out[ob + 0]   = a0 * inv;
    out[ob + 256] = a1 * inv;
    out[ob + 512] = a2 * inv;
    out[ob + 768] = a3 * inv;
}

extern "C" void kernel_launch(void* const* d_in, const int* in_sizes, int n_in,
                              void* d_out, int out_size, void* d_ws, size_t ws_size,
                              hipStream_t stream) {
    const float* x    = (const float*)d_in[0];
    const int*   posv = (const int*)d_in[1];
    const int*   posh = (const int*)d_in[2];
    float*       out  = (float*)d_out;

    char* ws = (char*)d_ws;
    float* G2f    = (float*)(ws + OFF_G2);
    int*   cntv   = (int*)(ws + OFF_CNTV);
    int*   cnth   = (int*)(ws + OFF_CNTH);
    float* invden = (float*)(ws + OFF_INVDEN);
    int*   tokv   = (int*)(ws + OFF_TOKV);
    int*   tokh   = (int*)(ws + OFF_TOKH);
    float* B1     = (float*)(ws + OFF_B1);

    const size_t needFull = (size_t)OFF_B1 + (size_t)NB * B1_SLAB;   // ~143 MB
    const size_t needLoop = (size_t)OFF_B1 + B1_SLAB;                // ~25 MB

    if (ws_size >= needFull) {
        k1_bucket<<<NB * 32, 256, 0, stream>>>(posv, posh, tokv, tokh, cntv, cnth, G2f);
        kden<<<NB * 8, 256, 0, stream>>>(posv, posh, G2f, invden, 0);
        k2_convh<<<NB * 1024, 256, 0, stream>>>(x, posh, tokv, cntv, G2f, B1, 0);
        k3_convv<<<NB * 1024, 256, 0, stream>>>(posv, tokh, cnth, G2f, B1, invden, out, 0);
    } else if (ws_size >= needLoop) {
        k1_bucket<<<NB * 32, 256, 0, stream>>>(posv, posh, tokv, tokh, cntv, cnth, G2f);
        for (int b = 0; b < NB; b++) {
            kden<<<8, 256, 0, stream>>>(posv, posh, G2f, invden, b);
            k2_convh<<<1024, 256, 0, stream>>>(x, posh, tokv, cntv, G2f, B1, b);
            k3_convv<<<1024, 256, 0, stream>>>(posv, tokh, cnth, G2f, B1, invden, out, b);
        }
    } else {
        k_naive<<<NB * NT, 256, 0, stream>>>(x, posv, posh, out);
    }
}

// Round 4
// 134.695 us; speedup vs baseline: 3.4245x; 1.6023x over previous
//
#include <hip/hip_runtime.h>
#include <hip/hip_bf16.h>

// Problem constants (fixed by setup_inputs): B=8, T=2048, D=1024, positions in [0,64).
#define NB 8
#define NT 2048
#define ND 1024
#define CAP 2048       // max tokens per bucket (worst case all T in one bucket)

// ---------------------------------------------------------------------------
// Workspace layout (byte offsets):
//   pad    : 64 floats of zeros (shift-register conv reads G2f[-1])      @ 0
//   G2f    : 128 floats  g2[k] = exp(-(k-63)^2/512), valid k in [0,126]  @ 256
//   cntv   : NB*64 int                                                   @ 768
//   cnth   : NB*64 int                                                   @ 2816
//   invden : NB*64*64 float  1/denominator for a token at (pv,ph)        @ 4864
//   tokv   : NB*64*CAP int   (token ids bucketed by posv)                @ 135936
//   tokh   : NB*64*CAP int   (token ids bucketed by posh)                @ 4330240
//   B1     : NB*64*64*1024 float   [b][pv][q=ph'][d]                     @ 8524544
// ---------------------------------------------------------------------------
#define OFF_G2     256
#define OFF_CNTV   768
#define OFF_CNTH   2816
#define OFF_INVDEN 4864
#define OFF_TOKV   135936
#define OFF_TOKH   4330240
#define OFF_B1     8524544
#define B1_SLAB    ((size_t)64 * 64 * 1024 * 4)   // bytes per batch slab (16 MB)

// K1: deterministic CSR bucket lists (by posv and by posh) via wave ballot
// compaction (no atomics -> bitwise deterministic). Block 0 fills the g table
// (with a 64-float zero pad below it). One (bucket,axis) task per wave.
__global__ __launch_bounds__(256) void k1_bucket(
    const int* __restrict__ posv, const int* __restrict__ posh,
    int* __restrict__ tokv, int* __restrict__ tokh,
    int* __restrict__ cntv, int* __restrict__ cnth,
    float* __restrict__ gbase)   // = ws base; table lives at gbase+64
{
    int b    = blockIdx.x >> 5;      // NB*32 blocks
    int blk  = blockIdx.x & 31;
    int wave = threadIdx.x >> 6;
    int lane = threadIdx.x & 63;

    if (blockIdx.x == 0 && threadIdx.x < 192) {
        int k = (int)threadIdx.x - 64;     // table index; <0 = pad
        float v = 0.0f;
        if (k >= 0 && k < 127) {
            int r = k - 63;
            v = expf(-(float)(r * r) * (1.0f / 512.0f));
        }
        gbase[threadIdx.x] = v;
    }

    int task   = blk * 4 + wave;                // 0..127
    int bucket = task & 63;
    int use_ph = task >> 6;
    const int* pos = use_ph ? posh : posv;
    int* tok = (use_ph ? tokh : tokv) + ((size_t)(b * 64 + bucket)) * CAP;
    int* cnt = use_ph ? cnth : cntv;

    int vals[32];
#pragma unroll
    for (int k = 0; k < 32; k++) vals[k] = pos[b * NT + k * 64 + lane];

    unsigned long long lmask = (1ull << lane) - 1ull;
    int cursor = 0;
#pragma unroll 4
    for (int k = 0; k < 32; k++) {
        bool hit = (vals[k] == bucket);
        unsigned long long m = __ballot(hit);
        if (hit) tok[cursor + __popcll(m & lmask)] = k * 64 + lane;
        cursor += (int)__popcll(m);
    }
    if (lane == 0) cnt[b * 64 + bucket] = cursor;
}

// KDEN: denominator table. den[pv][ph] = sum_{j,k} hist[j][k] g(pv-j) g(ph-k).
// Integer LDS-atomic histogram (deterministic), then two 64x64 mini-matmuls.
__global__ __launch_bounds__(256) void kden(
    const int* __restrict__ posv, const int* __restrict__ posh,
    const float* __restrict__ G2f, float* __restrict__ invden, int b0)
{
    int b   = b0 + (blockIdx.x >> 3);
    int phg = blockIdx.x & 7;
    int tid = threadIdx.x;

    __shared__ int   hist[64][64];
    __shared__ float g2s[128];
    __shared__ float tmp[64][8];

#pragma unroll
    for (int k = 0; k < 16; k++) ((int*)hist)[tid + (k << 8)] = 0;
    if (tid < 128) g2s[tid] = G2f[tid];
    __syncthreads();
#pragma unroll
    for (int k = 0; k < 8; k++) {
        int t = (k << 8) + tid;
        atomicAdd(&hist[posv[b * NT + t]][posh[b * NT + t]], 1);
    }
    __syncthreads();
#pragma unroll
    for (int c = 0; c < 2; c++) {
        int cell = (c << 8) + tid;        // 512 cells: 64 j x 8 phl
        int j    = cell >> 3;
        int phl  = cell & 7;
        int ph   = (phg << 3) + phl;
        float s = 0.f;
        for (int k = 0; k < 64; k++)
            s += (float)hist[j][k] * g2s[63 + k - ph];
        tmp[j][phl] = s;
    }
    __syncthreads();
#pragma unroll
    for (int c = 0; c < 2; c++) {
        int cell = (c << 8) + tid;
        int pv   = cell >> 3;
        int phl  = cell & 7;
        int ph   = (phg << 3) + phl;
        float s = 0.f;
        for (int j = 0; j < 64; j++)
            s += g2s[63 + j - pv] * tmp[j][phl];
        invden[(b * 64 + pv) * 64 + ph] = 1.0f / s;
    }
}

// K2: h-conv from token lists.
//   B1[b][pv][q][d] = sum_{t: posv_t==pv} g(q - posh_t) * x[b][t][d]
// Wave w owns q-tile [16w,16w+16); lane owns d within a 64-wide d-chunk.
// KEY FIX vs round 3: the g-window offset is readfirstlane'd so the pointer
// is provably wave-uniform -> s_load (SMEM pipe) instead of per-lane VMEM
// broadcast loads (which were 64 VMEM per 64 FMA = the 15% VALUBusy).
__global__ __launch_bounds__(256) void k2_convh(
    const float* __restrict__ x, const int* __restrict__ posh,
    const int* __restrict__ tokv, const int* __restrict__ cntv,
    const float* __restrict__ G2f, float* __restrict__ B1, int b0)
{
    int pv   = blockIdx.x & 63;
    int dc   = (blockIdx.x >> 6) & 15;
    int b    = b0 + (blockIdx.x >> 10);
    int tid  = threadIdx.x;
    int lane = tid & 63;
    int d0   = dc << 6;

    int goff = __builtin_amdgcn_readfirstlane(63 + ((tid >> 6) << 4));  // 63 + 16w
    int wq   = goff - 63;                                               // 16w (scalar)

    int n = cntv[b * 64 + pv];
    const int* toks = tokv + ((size_t)(b * 64 + pv)) * CAP;
    const float* xb = x + (((size_t)b * NT) << 10) + d0 + lane;

    float acc[16];
#pragma unroll
    for (int q = 0; q < 16; q++) acc[q] = 0.f;

    __shared__ int s_t[256];
    __shared__ int s_ph[256];

    for (int base = 0; base < n; base += 256) {
        int m = min(256, n - base);
        __syncthreads();
        if (tid < m) {
            int t = toks[base + tid];
            s_t[tid]  = t;
            s_ph[tid] = posh[b * NT + t];
        }
        __syncthreads();
        int i = 0;
        for (; i + 4 <= m; i += 4) {
            float xv[4]; const float* gp[4];
#pragma unroll
            for (int j = 0; j < 4; j++) {
                int t  = __builtin_amdgcn_readfirstlane(s_t[i + j]);
                int ph = __builtin_amdgcn_readfirstlane(s_ph[i + j]);
                xv[j] = xb[(size_t)t << 10];
                gp[j] = G2f + (goff - ph);     // fully scalar address
            }
#pragma unroll
            for (int q = 0; q < 16; q++) {
                float a = acc[q];
#pragma unroll
                for (int j = 0; j < 4; j++)
                    a = fmaf(gp[j][q], xv[j], a);
                acc[q] = a;
            }
        }
        for (; i < m; i++) {
            int t  = __builtin_amdgcn_readfirstlane(s_t[i]);
            int ph = __builtin_amdgcn_readfirstlane(s_ph[i]);
            float xv = xb[(size_t)t << 10];
            const float* gp = G2f + (goff - ph);
#pragma unroll
            for (int q = 0; q < 16; q++)
                acc[q] = fmaf(gp[q], xv, acc[q]);
        }
    }

    float* B1p = B1 + (((size_t)(b - b0)) << 22) + (((size_t)pv) << 16)
               + (((size_t)wq) << 10) + d0 + lane;
#pragma unroll
    for (int q = 0; q < 16; q++)
        B1p[(size_t)q << 10] = acc[q];
}

// K3: dense v-conv fused with token gather + normalization.
// Stage u[j][d] = B1[b][j][ph][d] in LDS; y[pv'][d] = sum_j g(pv'-j) u[j][d]
// via a register shift-window over g (1 scalar g-load + 16 FMA per tap);
// park y in LDS; scatter out[t][d] = y[pv_t][d] * invden[pv_t][ph].
__global__ __launch_bounds__(256) void k3_convv(
    const int* __restrict__ posv,
    const int* __restrict__ tokh, const int* __restrict__ cnth,
    const float* __restrict__ G2f, const float* __restrict__ B1,
    const float* __restrict__ invden, float* __restrict__ out, int b0)
{
    int ph   = blockIdx.x & 63;
    int dc   = (blockIdx.x >> 6) & 15;
    int b    = b0 + (blockIdx.x >> 10);
    int tid  = threadIdx.x;
    int lane = tid & 63;
    int w    = tid >> 6;
    int d0   = dc << 6;

    int n = cnth[b * 64 + ph];
    if (n == 0) return;               // uniform across block: safe

    __shared__ float u[64][64];
    __shared__ float y[64][64];
    __shared__ int   s_t[256];
    __shared__ int   s_pv[256];
    __shared__ float s_iv[256];

    int wq = __builtin_amdgcn_readfirstlane((tid >> 6) << 4);   // 16w, scalar

    // stage u: 16 independent 256B wave-loads per wave
    const float* B1p = B1 + (((size_t)(b - b0)) << 22) + (((size_t)ph) << 10)
                     + d0 + lane;
#pragma unroll
    for (int k = 0; k < 16; k++) {
        int j = (k << 2) + w;
        u[j][lane] = B1p[(size_t)j << 16];
    }

    // init g shift-window for j=0: gw[q] = g(16w + q - 0)
    float gw[16];
#pragma unroll
    for (int k = 0; k < 16; k++) gw[k] = G2f[63 + wq + k];

    float acc[16];
#pragma unroll
    for (int q = 0; q < 16; q++) acc[q] = 0.f;

    __syncthreads();

#pragma unroll
    for (int j = 0; j < 64; j++) {
        float uv = u[j][lane];
#pragma unroll
        for (int q = 0; q < 16; q++)
            acc[q] = fmaf(gw[q], uv, acc[q]);
        // shift window for j+1 (unrolled -> pure renaming, no v_movs)
#pragma unroll
        for (int k = 15; k > 0; k--) gw[k] = gw[k - 1];
        gw[0] = G2f[62 + wq - j];     // index -1 at w=0,j=63 -> zero pad below table
    }

#pragma unroll
    for (int q = 0; q < 16; q++) y[wq + q][lane] = acc[q];
    // first __syncthreads in the scatter loop orders y-writes vs y-reads

    const int* toks = tokh + ((size_t)(b * 64 + ph)) * CAP;
    float* outb = out + (((size_t)b * NT) << 10) + d0 + lane;
    const float* ivb = invden + (b * 64) * 64 + ph;

    for (int base = 0; base < n; base += 256) {
        int m = min(256, n - base);
        __syncthreads();
        if (tid < m) {
            int t  = toks[base + tid];
            int pv = posv[b * NT + t];
            s_t[tid]  = t;
            s_pv[tid] = pv;
            s_iv[tid] = ivb[pv * 64];
        }
        __syncthreads();
        for (int i = w; i < m; i += 4) {
            int t  = __builtin_amdgcn_readfirstlane(s_t[i]);
            int pv = __builtin_amdgcn_readfirstlane(s_pv[i]);
            float iv = s_iv[i];
            outb[(size_t)t << 10] = y[pv][lane] * iv;
        }
    }
}

// Safety-net fallback (no workspace needed): direct O(T^2 * D) attention.
__global__ __launch_bounds__(256) void k_naive(
    const float* __restrict__ x, const int* __restrict__ posv,
    const int* __restrict__ posh, float* __restrict__ out)
{
    int t   = blockIdx.x & (NT - 1);
    int b   = blockIdx.x >> 11;
    int tid = threadIdx.x;

    __shared__ float s_w[NT];
    __shared__ float s_red[256];

    int pvt = posv[b * NT + t];
    int pht = posh[b * NT + t];

    float dsum = 0.0f;
    for (int s = tid; s < NT; s += 256) {
        int dv = pvt - posv[b * NT + s];
        int dh = pht - posh[b * NT + s];
        float w = expf(-(float)(dv * dv + dh * dh) * (1.0f / 512.0f));
        s_w[s] = w;
        dsum += w;
    }
    s_red[tid] = dsum;
    __syncthreads();
    for (int off = 128; off > 0; off >>= 1) {
        if (tid < off) s_red[tid] += s_red[tid + off];
        __syncthreads();
    }
    float inv = 1.0f / s_red[0];

    float a0 = 0.f, a1 = 0.f, a2 = 0.f, a3 = 0.f;
    for (int s = 0; s < NT; s++) {
        float w = s_w[s];
        const float* xr = x + (((size_t)(b * NT + s)) << 10);
        a0 = fmaf(w, xr[tid + 0],   a0);
        a1 = fmaf(w, xr[tid + 256], a1);
        a2 = fmaf(w, xr[tid + 512], a2);
        a3 = fmaf(w, xr[tid + 768], a3);
    }
    size_t ob = (((size_t)(b * NT + t)) << 10) + tid;
    out[ob + 0]   = a0 * inv;
    out[ob + 256] = a1 * inv;
    out[ob + 512] = a2 * inv;
    out[ob + 768] = a3 * inv;
}

extern "C" void kernel_launch(void* const* d_in, const int* in_sizes, int n_in,
                              void* d_out, int out_size, void* d_ws, size_t ws_size,
                              hipStream_t stream) {
    const float* x    = (const float*)d_in[0];
    const int*   posv = (const int*)d_in[1];
    const int*   posh = (const int*)d_in[2];
    float*       out  = (float*)d_out;

    char* ws = (char*)d_ws;
    float* gbase  = (float*)ws;               // pad + table
    float* G2f    = (float*)(ws + OFF_G2);
    int*   cntv   = (int*)(ws + OFF_CNTV);
    int*   cnth   = (int*)(ws + OFF_CNTH);
    float* invden = (float*)(ws + OFF_INVDEN);
    int*   tokv   = (int*)(ws + OFF_TOKV);
    int*   tokh   = (int*)(ws + OFF_TOKH);
    float* B1     = (float*)(ws + OFF_B1);

    const size_t needFull = (size_t)OFF_B1 + (size_t)NB * B1_SLAB;   // ~143 MB
    const size_t needLoop = (size_t)OFF_B1 + B1_SLAB;                // ~25 MB

    if (ws_size >= needFull) {
        k1_bucket<<<NB * 32, 256, 0, stream>>>(posv, posh, tokv, tokh, cntv, cnth, gbase);
        kden<<<NB * 8, 256, 0, stream>>>(posv, posh, G2f, invden, 0);
        k2_convh<<<NB * 1024, 256, 0, stream>>>(x, posh, tokv, cntv, G2f, B1, 0);
        k3_convv<<<NB * 1024, 256, 0, stream>>>(posv, tokh, cnth, G2f, B1, invden, out, 0);
    } else if (ws_size >= needLoop) {
        k1_bucket<<<NB * 32, 256, 0, stream>>>(posv, posh, tokv, tokh, cntv, cnth, gbase);
        for (int b = 0; b < NB; b++) {
            kden<<<8, 256, 0, stream>>>(posv, posh, G2f, invden, b);
            k2_convh<<<1024, 256, 0, stream>>>(x, posh, tokv, cntv, G2f, B1, b);
            k3_convv<<<1024, 256, 0, stream>>>(posv, tokh, cnth, G2f, B1, invden, out, b);
        }
    } else {
        k_naive<<<NB * NT, 256, 0, stream>>>(x, posv, posh, out);
    }
}